// Round 11
// baseline (38.523 us; speedup 1.0000x reference)
//
#include <hip/hip_runtime.h>

// KernelExpansion: out[m] = sum_n sigma^2 * w[n] * exp(-0.5*||s_n - x_m||^2 / l^2)
// Round-11: cross-iteration software pipeline (acc double-buffer).
//  r8/r9/r10 all pinned at 35-37us regardless of occupancy/operand path ->
//  per-wave serial chain ds_read -> 12 MFMA -> 16 exp2 leaves the trans pipe
//  idle during the MFMA head of every iteration. Fix: two acc sets; iter t
//  issues iter-(t+1)'s ds_read+MFMAs BEFORE iter-t's exp2 block, so MFMA
//  latency hides under ~256 cyc of trans work. LDS-resident structure from
//  r10 kept (5 blocks/CU by LDS -> VGPR budget 102; pipeline set ~98).
//  p accumulated as packed v2f (2 pk_add per tile instead of 4 adds).
// C/D layout (verified r4 pass): acc[i] -> n-row q*4+i, m-col r.

#define LOG2E_F 1.4426950408889634f

typedef __attribute__((ext_vector_type(8))) short bf16x8;   // 8 bf16 = 4 VGPRs
typedef __attribute__((ext_vector_type(4))) float f32x4;
typedef float v2f_ __attribute__((ext_vector_type(2)));

constexpr int D      = 24;
constexpr int TILES  = 4;    // 16-col tiles per wave -> 64 m per wave
constexpr int NSPLIT = 32;   // n-chunks of 256 rows; blocks = (M/256)*NSPLIT
constexpr int CT     = 16;   // tiles per chunk (256 rows)
constexpr int TPB    = 256;

__device__ inline unsigned short f32_to_bf16_rne(float f) {
    unsigned u = __builtin_bit_cast(unsigned, f);
    u += 0x7fffu + ((u >> 16) & 1u);
    return (unsigned short)(u >> 16);
}
__device__ inline float bf16_to_f32(unsigned short h) {
    unsigned u = ((unsigned)h) << 16;
    return __builtin_bit_cast(float, u);
}

constexpr unsigned short BF16_ONE = 0x3F80;

__device__ inline float load_row24(const float* __restrict__ src, float* v) {
    float ssq = 0.f;
#pragma unroll
    for (int i = 0; i < 6; ++i) {
        float4 f = reinterpret_cast<const float4*>(src)[i];
        v[4*i+0] = f.x; v[4*i+1] = f.y; v[4*i+2] = f.z; v[4*i+3] = f.w;
    }
#pragma unroll
    for (int d = 0; d < 24; ++d) ssq = fmaf(v[d], v[d], ssq);
    return ssq;
}

// Write one row (32 cols, hi+lo) into LDS in fragment order.
// split_at_26: true -> cols {24,25}=1, {26,27}=splitval hi/lo  (x rows)
//              false -> cols {24,25}=splitval hi/lo, {26,27}=1 (s rows)
__device__ inline void stage_row(unsigned short* __restrict__ sm, int t,
                                 const float* __restrict__ v, float scale,
                                 float splitval, bool split_at_26) {
    unsigned short hi[32], lo[32];
#pragma unroll
    for (int d = 0; d < 24; ++d) {
        float vs = scale * v[d];
        unsigned short h = f32_to_bf16_rne(vs);
        hi[d] = h;
        lo[d] = f32_to_bf16_rne(vs - bf16_to_f32(h));
    }
    unsigned short shv = f32_to_bf16_rne(splitval);
    unsigned short slv = f32_to_bf16_rne(splitval - bf16_to_f32(shv));
    if (split_at_26) { hi[24] = BF16_ONE; hi[25] = BF16_ONE; hi[26] = shv; hi[27] = slv; }
    else             { hi[24] = shv; hi[25] = slv; hi[26] = BF16_ONE; hi[27] = BF16_ONE; }
    hi[28] = 0; hi[29] = 0; hi[30] = 0; hi[31] = 0;
#pragma unroll
    for (int d = 24; d < 32; ++d) lo[d] = 0;
    int sb = (t >> 4) * 512 + (t & 15) * 8;   // short index of (tile, r) slot base
#pragma unroll
    for (int q2 = 0; q2 < 4; ++q2) {
        bf16x8 vh, vl;
#pragma unroll
        for (int j2 = 0; j2 < 8; ++j2) { vh[j2] = (short)hi[q2*8+j2]; vl[j2] = (short)lo[q2*8+j2]; }
        *reinterpret_cast<bf16x8*>(sm + sb + q2 * 128) = vh;
        *reinterpret_cast<bf16x8*>(sm + 8192 + sb + q2 * 128) = vl;
    }
}

__global__ __launch_bounds__(TPB, 5) void ke_fused(
    const float* __restrict__ x, const float* __restrict__ s,
    const float* __restrict__ wts,
    const float* __restrict__ sigma_p, const float* __restrict__ length_p,
    float* __restrict__ out, int M, int N, int MGRP) {
    __shared__ __align__(16) unsigned short sm[16384];  // 32KB: hi [0,8192) lo [8192,16384)
    int t    = threadIdx.x;
    int lane = t & 63;
    int wv   = t >> 6;
    int mg   = blockIdx.x % MGRP;
    int ns   = blockIdx.x / MGRP;
    int r    = lane & 15;

    float l    = length_p[0];
    float c2   = -0.5f * LOG2E_F / (l * l);
    float m2c2 = -2.f * c2;
    float sg   = sigma_p[0];

    float v[24];
    // ---- phase 1: stage this block's 256 x-rows, pick up B fragments
    {
        int row = mg * 256 + t;
        float ssq = load_row24(x + (size_t)row * D, v);
        stage_row(sm, t, v, 1.f, c2 * ssq, true);
    }
    __syncthreads();
    bf16x8 bh[TILES], bl[TILES];
#pragma unroll
    for (int j = 0; j < TILES; ++j) {
        int si = ((wv * 4 + j) * 64 + lane) * 8;
        bh[j] = *reinterpret_cast<const bf16x8*>(sm + si);
        bl[j] = *reinterpret_cast<const bf16x8*>(sm + 8192 + si);
    }
#pragma unroll
    for (int j = 0; j < TILES; ++j) { asm("" : "+v"(bh[j]), "+v"(bl[j])); }
    __syncthreads();
    // ---- phase 2: stage this block's 256 s-rows (n-chunk) into the same LDS
    {
        int row = ns * 256 + t;
        float ssq = load_row24(s + (size_t)row * D, v);
        float lwt = __log2f(sg * sg * wts[row]) + c2 * ssq;
        lwt = fmaxf(lwt, -20000.f);              // w -> 0: finite, exp2 -> 0
        stage_row(sm, t, v, m2c2, lwt, false);
    }
    __syncthreads();

    // ---- main loop, software-pipelined: compute MFMAs for tile tt while
    // running the exp2/accumulate block of tile tt-1.
    v2f_ p2[TILES] = {{0.f, 0.f}, {0.f, 0.f}, {0.f, 0.f}, {0.f, 0.f}};

    f32x4 acc[TILES];
    {
        bf16x8 ah = *reinterpret_cast<const bf16x8*>(sm + (size_t)lane * 8);
        bf16x8 al = *reinterpret_cast<const bf16x8*>(sm + 8192 + (size_t)lane * 8);
#pragma unroll
        for (int j = 0; j < TILES; ++j) {
            f32x4 z = {0.f, 0.f, 0.f, 0.f};
            acc[j] = __builtin_amdgcn_mfma_f32_16x16x32_bf16(ah, bh[j], z, 0, 0, 0);
            acc[j] = __builtin_amdgcn_mfma_f32_16x16x32_bf16(al, bh[j], acc[j], 0, 0, 0);
            acc[j] = __builtin_amdgcn_mfma_f32_16x16x32_bf16(ah, bl[j], acc[j], 0, 0, 0);
        }
    }
#pragma unroll 1
    for (int tt = 1; tt < CT; ++tt) {
        // next iteration's operands + MFMAs issue first...
        bf16x8 ah = *reinterpret_cast<const bf16x8*>(sm + ((size_t)tt * 64 + lane) * 8);
        bf16x8 al = *reinterpret_cast<const bf16x8*>(sm + 8192 + ((size_t)tt * 64 + lane) * 8);
        f32x4 accn[TILES];
#pragma unroll
        for (int j = 0; j < TILES; ++j) {
            f32x4 z = {0.f, 0.f, 0.f, 0.f};
            accn[j] = __builtin_amdgcn_mfma_f32_16x16x32_bf16(ah, bh[j], z, 0, 0, 0);
            accn[j] = __builtin_amdgcn_mfma_f32_16x16x32_bf16(al, bh[j], accn[j], 0, 0, 0);
            accn[j] = __builtin_amdgcn_mfma_f32_16x16x32_bf16(ah, bl[j], accn[j], 0, 0, 0);
        }
        // ...then the previous iteration's trans block (independent of the above)
#pragma unroll
        for (int j = 0; j < TILES; ++j) {
            float e0 = __builtin_amdgcn_exp2f(acc[j][0]);
            float e1 = __builtin_amdgcn_exp2f(acc[j][1]);
            float e2 = __builtin_amdgcn_exp2f(acc[j][2]);
            float e3 = __builtin_amdgcn_exp2f(acc[j][3]);
            v2f_ a = {e0, e2};
            v2f_ b = {e1, e3};
            p2[j] += a + b;
        }
#pragma unroll
        for (int j = 0; j < TILES; ++j) acc[j] = accn[j];
    }
    // epilogue: trans block of the last tile
#pragma unroll
    for (int j = 0; j < TILES; ++j) {
        float e0 = __builtin_amdgcn_exp2f(acc[j][0]);
        float e1 = __builtin_amdgcn_exp2f(acc[j][1]);
        float e2 = __builtin_amdgcn_exp2f(acc[j][2]);
        float e3 = __builtin_amdgcn_exp2f(acc[j][3]);
        v2f_ a = {e0, e2};
        v2f_ b = {e1, e3};
        p2[j] += a + b;
    }

    // reduce over the 4 q-quarters (column r fixed) and accumulate
    float p[TILES];
#pragma unroll
    for (int j = 0; j < TILES; ++j) {
        p[j] = p2[j].x + p2[j].y;
        p[j] += __shfl_xor(p[j], 16, 64);
        p[j] += __shfl_xor(p[j], 32, 64);
    }
    if (lane < 16) {
        int m0 = mg * 256 + wv * 64;
#pragma unroll
        for (int j = 0; j < TILES; ++j)
            atomicAdd(&out[m0 + j * 16 + r], p[j]);
    }
}

// ---- fallback: fp32 VALU kernel (no workspace needed)
constexpr int MPT  = 2;
constexpr int MBLK = TPB * MPT;

__global__ __launch_bounds__(TPB) void ke_plain(
    const float* __restrict__ x, const float* __restrict__ samples,
    const float* __restrict__ weights, const float* __restrict__ sigma_p,
    const float* __restrict__ length_p, float* __restrict__ out,
    int M, int N, int nsplit, int chunk) {
    int mb = blockIdx.x / nsplit;
    int ns = blockIdx.x - mb * nsplit;
    int t  = threadIdx.x;
    int m0 = mb * MBLK + t;
    int m1 = m0 + TPB;
    int m0c = (m0 < M) ? m0 : 0;
    int m1c = (m1 < M) ? m1 : 0;

    v2f_ xaq[D / 2], xbq[D / 2];
    const v2f_* xp0 = reinterpret_cast<const v2f_*>(x + (size_t)m0c * D);
    const v2f_* xp1 = reinterpret_cast<const v2f_*>(x + (size_t)m1c * D);
#pragma unroll
    for (int qq = 0; qq < D / 2; ++qq) { xaq[qq] = xp0[qq]; xbq[qq] = xp1[qq]; }
#pragma unroll
    for (int qq = 0; qq < D / 2; ++qq) { asm("" : "+v"(xaq[qq])); asm("" : "+v"(xbq[qq])); }

    float l   = length_p[0];
    float c   = -0.5f * LOG2E_F / (l * l);
    float m2c = -2.f * c;
    float sg  = sigma_p[0];
    float sg2 = sg * sg;

    v2f_ qa = {0.f, 0.f}, qb = {0.f, 0.f};
#pragma unroll
    for (int qq = 0; qq < D / 2; ++qq) {
        qa = __builtin_elementwise_fma(xaq[qq], xaq[qq], qa);
        qb = __builtin_elementwise_fma(xbq[qq], xbq[qq], qb);
    }
    float cxa = c * (qa.x + qa.y);
    float cxb = c * (qb.x + qb.y);

    float acc0 = 0.f, acc1 = 0.f;
    int n0 = ns * chunk;
    int n1 = n0 + chunk;
    if (n1 > N) n1 = N;
#pragma unroll 2
    for (int n = n0; n < n1; ++n) {
        const v2f_* s2 = reinterpret_cast<const v2f_*>(samples + (size_t)n * D);
        v2f_ da = {0.f, 0.f}, db = {0.f, 0.f}, sq = {0.f, 0.f};
#pragma unroll
        for (int qq = 0; qq < D / 2; ++qq) {
            v2f_ sv = s2[qq];
            sq = __builtin_elementwise_fma(sv, sv, sq);
            da = __builtin_elementwise_fma(sv, xaq[qq], da);
            db = __builtin_elementwise_fma(sv, xbq[qq], db);
        }
        float cn = c * (sq.x + sq.y);
        float wn = sg2 * weights[n];
        float e0 = fmaf(m2c, da.x + da.y, cn);
        float e1 = fmaf(m2c, db.x + db.y, cn);
        acc0 = fmaf(wn, __builtin_amdgcn_exp2f(e0), acc0);
        acc1 = fmaf(wn, __builtin_amdgcn_exp2f(e1), acc1);
    }
    if (m0 < M) atomicAdd(&out[m0], acc0 * __builtin_amdgcn_exp2f(cxa));
    if (m1 < M) atomicAdd(&out[m1], acc1 * __builtin_amdgcn_exp2f(cxb));
}

extern "C" void kernel_launch(void* const* d_in, const int* in_sizes, int n_in,
                              void* d_out, int out_size, void* d_ws, size_t ws_size,
                              hipStream_t stream) {
    const float* x       = (const float*)d_in[0];
    const float* samples = (const float*)d_in[1];
    const float* weights = (const float*)d_in[2];
    const float* sigma_p = (const float*)d_in[3];
    const float* length_p= (const float*)d_in[4];
    float* out = (float*)d_out;

    int M = in_sizes[0] / D;
    int N = in_sizes[1] / D;

    hipMemsetAsync(out, 0, (size_t)out_size * sizeof(float), stream);

    bool fused_ok = (M % 256) == 0 && (N == NSPLIT * CT * 16) && out_size >= M;

    if (fused_ok) {
        int MGRP   = M / 256;                 // 64
        int blocks = MGRP * NSPLIT;           // 2048
        ke_fused<<<dim3(blocks), dim3(TPB), 0, stream>>>(
            x, samples, weights, sigma_p, length_p, out, M, N, MGRP);
    } else {
        int mbcnt  = (M + MBLK - 1) / MBLK;
        int nsplit = 2048 / (mbcnt > 0 ? mbcnt : 1);
        if (nsplit < 1) nsplit = 1;
        if (nsplit > N) nsplit = N;
        int chunk = (N + nsplit - 1) / nsplit;
        ke_plain<<<dim3(mbcnt * nsplit), dim3(TPB), 0, stream>>>(
            x, samples, weights, sigma_p, length_p, out, M, N, nsplit, chunk);
    }
}

// Round 13
// 36.488 us; speedup vs baseline: 1.0558x; 1.0558x over previous
//
#include <hip/hip_runtime.h>

// KernelExpansion: out[m] = sum_n sigma^2 * w[n] * exp(-0.5*||s_n - x_m||^2 / l^2)
// Round-13 (= r12 resubmit after infra failure): sched_barrier-enforced pipeline.
//  r11 post-mortem: VGPR=48 proves the compiler DELETED the acc double-buffer
//  (sank exp2 back after each MFMA chain). Fix: named ping-pong accA/accB and
//  __builtin_amdgcn_sched_barrier(0) between MFMA(t) and exp2(t-1) so neither
//  can cross; each inter-barrier region = {exp2(t-1) || ld+MFMA(t)} mixing.
//  Plus persistent zero C-in quad (kills 16 zero-init movs/iter).
//  Base structure from r10: single fused kernel, s-chunk+x staged in 32KB LDS
//  in fragment order; K-pad constant folding (acc IS the exp2 argument).
// C/D layout (verified r4 pass): acc[i] -> n-row q*4+i, m-col r.

#define LOG2E_F 1.4426950408889634f

typedef __attribute__((ext_vector_type(8))) short bf16x8;   // 8 bf16 = 4 VGPRs
typedef __attribute__((ext_vector_type(4))) float f32x4;
typedef float v2f_ __attribute__((ext_vector_type(2)));

constexpr int D      = 24;
constexpr int TILES  = 4;    // 16-col tiles per wave -> 64 m per wave
constexpr int NSPLIT = 32;   // n-chunks of 256 rows; blocks = (M/256)*NSPLIT
constexpr int CT     = 16;   // tiles per chunk (256 rows)
constexpr int TPB    = 256;

__device__ inline unsigned short f32_to_bf16_rne(float f) {
    unsigned u = __builtin_bit_cast(unsigned, f);
    u += 0x7fffu + ((u >> 16) & 1u);
    return (unsigned short)(u >> 16);
}
__device__ inline float bf16_to_f32(unsigned short h) {
    unsigned u = ((unsigned)h) << 16;
    return __builtin_bit_cast(float, u);
}

constexpr unsigned short BF16_ONE = 0x3F80;

__device__ inline float load_row24(const float* __restrict__ src, float* v) {
    float ssq = 0.f;
#pragma unroll
    for (int i = 0; i < 6; ++i) {
        float4 f = reinterpret_cast<const float4*>(src)[i];
        v[4*i+0] = f.x; v[4*i+1] = f.y; v[4*i+2] = f.z; v[4*i+3] = f.w;
    }
#pragma unroll
    for (int d = 0; d < 24; ++d) ssq = fmaf(v[d], v[d], ssq);
    return ssq;
}

// Write one row (32 cols, hi+lo) into LDS in fragment order.
__device__ inline void stage_row(unsigned short* __restrict__ sm, int t,
                                 const float* __restrict__ v, float scale,
                                 float splitval, bool split_at_26) {
    unsigned short hi[32], lo[32];
#pragma unroll
    for (int d = 0; d < 24; ++d) {
        float vs = scale * v[d];
        unsigned short h = f32_to_bf16_rne(vs);
        hi[d] = h;
        lo[d] = f32_to_bf16_rne(vs - bf16_to_f32(h));
    }
    unsigned short shv = f32_to_bf16_rne(splitval);
    unsigned short slv = f32_to_bf16_rne(splitval - bf16_to_f32(shv));
    if (split_at_26) { hi[24] = BF16_ONE; hi[25] = BF16_ONE; hi[26] = shv; hi[27] = slv; }
    else             { hi[24] = shv; hi[25] = slv; hi[26] = BF16_ONE; hi[27] = BF16_ONE; }
    hi[28] = 0; hi[29] = 0; hi[30] = 0; hi[31] = 0;
#pragma unroll
    for (int d = 24; d < 32; ++d) lo[d] = 0;
    int sb = (t >> 4) * 512 + (t & 15) * 8;   // short index of (tile, r) slot base
#pragma unroll
    for (int q2 = 0; q2 < 4; ++q2) {
        bf16x8 vh, vl;
#pragma unroll
        for (int j2 = 0; j2 < 8; ++j2) { vh[j2] = (short)hi[q2*8+j2]; vl[j2] = (short)lo[q2*8+j2]; }
        *reinterpret_cast<bf16x8*>(sm + sb + q2 * 128) = vh;
        *reinterpret_cast<bf16x8*>(sm + 8192 + sb + q2 * 128) = vl;
    }
}

__global__ __launch_bounds__(TPB, 5) void ke_fused(
    const float* __restrict__ x, const float* __restrict__ s,
    const float* __restrict__ wts,
    const float* __restrict__ sigma_p, const float* __restrict__ length_p,
    float* __restrict__ out, int M, int N, int MGRP) {
    __shared__ __align__(16) unsigned short sm[16384];  // 32KB: hi [0,8192) lo [8192,16384)
    int t    = threadIdx.x;
    int lane = t & 63;
    int wv   = t >> 6;
    int mg   = blockIdx.x % MGRP;
    int ns   = blockIdx.x / MGRP;
    int r    = lane & 15;

    float l    = length_p[0];
    float c2   = -0.5f * LOG2E_F / (l * l);
    float m2c2 = -2.f * c2;
    float sg   = sigma_p[0];

    float v[24];
    // ---- phase 1: stage this block's 256 x-rows, pick up B fragments
    {
        int row = mg * 256 + t;
        float ssq = load_row24(x + (size_t)row * D, v);
        stage_row(sm, t, v, 1.f, c2 * ssq, true);
    }
    __syncthreads();
    bf16x8 bh[TILES], bl[TILES];
#pragma unroll
    for (int j = 0; j < TILES; ++j) {
        int si = ((wv * 4 + j) * 64 + lane) * 8;
        bh[j] = *reinterpret_cast<const bf16x8*>(sm + si);
        bl[j] = *reinterpret_cast<const bf16x8*>(sm + 8192 + si);
    }
#pragma unroll
    for (int j = 0; j < TILES; ++j) { asm("" : "+v"(bh[j]), "+v"(bl[j])); }
    __syncthreads();
    // ---- phase 2: stage this block's 256 s-rows (n-chunk) into the same LDS
    {
        int row = ns * 256 + t;
        float ssq = load_row24(s + (size_t)row * D, v);
        float lwt = __log2f(sg * sg * wts[row]) + c2 * ssq;
        lwt = fmaxf(lwt, -20000.f);              // w -> 0: finite, exp2 -> 0
        stage_row(sm, t, v, m2c2, lwt, false);
    }
    __syncthreads();

    // ---- main loop: software pipeline forced by sched_barrier(0).
    f32x4 zeroq = {0.f, 0.f, 0.f, 0.f};
    asm("" : "+v"(zeroq));                       // persistent zero C-in

    v2f_ p2[TILES] = {{0.f, 0.f}, {0.f, 0.f}, {0.f, 0.f}, {0.f, 0.f}};
    f32x4 accA[TILES], accB[TILES];

#define KE_MFMA_BLOCK(ACC, TT)                                                        \
    {                                                                                 \
        bf16x8 ah = *reinterpret_cast<const bf16x8*>(sm + ((size_t)(TT) * 64 + lane) * 8);        \
        bf16x8 al = *reinterpret_cast<const bf16x8*>(sm + 8192 + ((size_t)(TT) * 64 + lane) * 8); \
        _Pragma("unroll")                                                             \
        for (int j = 0; j < TILES; ++j) {                                             \
            ACC[j] = __builtin_amdgcn_mfma_f32_16x16x32_bf16(ah, bh[j], zeroq, 0, 0, 0); \
            ACC[j] = __builtin_amdgcn_mfma_f32_16x16x32_bf16(al, bh[j], ACC[j], 0, 0, 0); \
            ACC[j] = __builtin_amdgcn_mfma_f32_16x16x32_bf16(ah, bl[j], ACC[j], 0, 0, 0); \
        }                                                                             \
    }

#define KE_EXP_BLOCK(ACC)                                                             \
    {                                                                                 \
        _Pragma("unroll")                                                             \
        for (int j = 0; j < TILES; ++j) {                                             \
            float e0 = __builtin_amdgcn_exp2f(ACC[j][0]);                             \
            float e1 = __builtin_amdgcn_exp2f(ACC[j][1]);                             \
            float e2 = __builtin_amdgcn_exp2f(ACC[j][2]);                             \
            float e3 = __builtin_amdgcn_exp2f(ACC[j][3]);                             \
            v2f_ a = {e0, e2};                                                        \
            v2f_ b = {e1, e3};                                                        \
            p2[j] += a + b;                                                           \
        }                                                                             \
    }

    KE_MFMA_BLOCK(accA, 0)                        // prologue: tile 0 -> accA
#pragma unroll 1
    for (int g = 0; g < (CT - 2) / 2; ++g) {      // 7 pairs: tiles 1..14
        int t1 = 2 * g + 1;
        KE_MFMA_BLOCK(accB, t1)                   // MFMA tile 2g+1
        __builtin_amdgcn_sched_barrier(0);
        KE_EXP_BLOCK(accA)                        // exp2 tile 2g (overlaps MFMA latency)
        KE_MFMA_BLOCK(accA, t1 + 1)               // MFMA tile 2g+2
        __builtin_amdgcn_sched_barrier(0);
        KE_EXP_BLOCK(accB)                        // exp2 tile 2g+1
    }
    KE_MFMA_BLOCK(accB, CT - 1)                   // tile 15
    __builtin_amdgcn_sched_barrier(0);
    KE_EXP_BLOCK(accA)                            // exp2 tile 14
    KE_EXP_BLOCK(accB)                            // exp2 tile 15

#undef KE_MFMA_BLOCK
#undef KE_EXP_BLOCK

    // reduce over the 4 q-quarters (column r fixed) and accumulate
    float p[TILES];
#pragma unroll
    for (int j = 0; j < TILES; ++j) {
        p[j] = p2[j].x + p2[j].y;
        p[j] += __shfl_xor(p[j], 16, 64);
        p[j] += __shfl_xor(p[j], 32, 64);
    }
    if (lane < 16) {
        int m0 = mg * 256 + wv * 64;
#pragma unroll
        for (int j = 0; j < TILES; ++j)
            atomicAdd(&out[m0 + j * 16 + r], p[j]);
    }
}

// ---- fallback: fp32 VALU kernel (no workspace needed)
constexpr int MPT  = 2;
constexpr int MBLK = TPB * MPT;

__global__ __launch_bounds__(TPB) void ke_plain(
    const float* __restrict__ x, const float* __restrict__ samples,
    const float* __restrict__ weights, const float* __restrict__ sigma_p,
    const float* __restrict__ length_p, float* __restrict__ out,
    int M, int N, int nsplit, int chunk) {
    int mb = blockIdx.x / nsplit;
    int ns = blockIdx.x - mb * nsplit;
    int t  = threadIdx.x;
    int m0 = mb * MBLK + t;
    int m1 = m0 + TPB;
    int m0c = (m0 < M) ? m0 : 0;
    int m1c = (m1 < M) ? m1 : 0;

    v2f_ xaq[D / 2], xbq[D / 2];
    const v2f_* xp0 = reinterpret_cast<const v2f_*>(x + (size_t)m0c * D);
    const v2f_* xp1 = reinterpret_cast<const v2f_*>(x + (size_t)m1c * D);
#pragma unroll
    for (int qq = 0; qq < D / 2; ++qq) { xaq[qq] = xp0[qq]; xbq[qq] = xp1[qq]; }
#pragma unroll
    for (int qq = 0; qq < D / 2; ++qq) { asm("" : "+v"(xaq[qq])); asm("" : "+v"(xbq[qq])); }

    float l   = length_p[0];
    float c   = -0.5f * LOG2E_F / (l * l);
    float m2c = -2.f * c;
    float sg  = sigma_p[0];
    float sg2 = sg * sg;

    v2f_ qa = {0.f, 0.f}, qb = {0.f, 0.f};
#pragma unroll
    for (int qq = 0; qq < D / 2; ++qq) {
        qa = __builtin_elementwise_fma(xaq[qq], xaq[qq], qa);
        qb = __builtin_elementwise_fma(xbq[qq], xbq[qq], qb);
    }
    float cxa = c * (qa.x + qa.y);
    float cxb = c * (qb.x + qb.y);

    float acc0 = 0.f, acc1 = 0.f;
    int n0 = ns * chunk;
    int n1 = n0 + chunk;
    if (n1 > N) n1 = N;
#pragma unroll 2
    for (int n = n0; n < n1; ++n) {
        const v2f_* s2 = reinterpret_cast<const v2f_*>(samples + (size_t)n * D);
        v2f_ da = {0.f, 0.f}, db = {0.f, 0.f}, sq = {0.f, 0.f};
#pragma unroll
        for (int qq = 0; qq < D / 2; ++qq) {
            v2f_ sv = s2[qq];
            sq = __builtin_elementwise_fma(sv, sv, sq);
            da = __builtin_elementwise_fma(sv, xaq[qq], da);
            db = __builtin_elementwise_fma(sv, xbq[qq], db);
        }
        float cn = c * (sq.x + sq.y);
        float wn = sg2 * weights[n];
        float e0 = fmaf(m2c, da.x + da.y, cn);
        float e1 = fmaf(m2c, db.x + db.y, cn);
        acc0 = fmaf(wn, __builtin_amdgcn_exp2f(e0), acc0);
        acc1 = fmaf(wn, __builtin_amdgcn_exp2f(e1), acc1);
    }
    if (m0 < M) atomicAdd(&out[m0], acc0 * __builtin_amdgcn_exp2f(cxa));
    if (m1 < M) atomicAdd(&out[m1], acc1 * __builtin_amdgcn_exp2f(cxb));
}

extern "C" void kernel_launch(void* const* d_in, const int* in_sizes, int n_in,
                              void* d_out, int out_size, void* d_ws, size_t ws_size,
                              hipStream_t stream) {
    const float* x       = (const float*)d_in[0];
    const float* samples = (const float*)d_in[1];
    const float* weights = (const float*)d_in[2];
    const float* sigma_p = (const float*)d_in[3];
    const float* length_p= (const float*)d_in[4];
    float* out = (float*)d_out;

    int M = in_sizes[0] / D;
    int N = in_sizes[1] / D;

    hipMemsetAsync(out, 0, (size_t)out_size * sizeof(float), stream);

    bool fused_ok = (M % 256) == 0 && (N == NSPLIT * CT * 16) && out_size >= M;

    if (fused_ok) {
        int MGRP   = M / 256;                 // 64
        int blocks = MGRP * NSPLIT;           // 2048
        ke_fused<<<dim3(blocks), dim3(TPB), 0, stream>>>(
            x, samples, weights, sigma_p, length_p, out, M, N, MGRP);
    } else {
        int mbcnt  = (M + MBLK - 1) / MBLK;
        int nsplit = 2048 / (mbcnt > 0 ? mbcnt : 1);
        if (nsplit < 1) nsplit = 1;
        if (nsplit > N) nsplit = N;
        int chunk = (N + nsplit - 1) / nsplit;
        ke_plain<<<dim3(mbcnt * nsplit), dim3(TPB), 0, stream>>>(
            x, samples, weights, sigma_p, length_p, out, M, N, nsplit, chunk);
    }
}

// Round 15
// 35.042 us; speedup vs baseline: 1.0993x; 1.0412x over previous
//
#include <hip/hip_runtime.h>

// KernelExpansion: out[m] = sum_n sigma^2 * w[n] * exp(-0.5*||s_n - x_m||^2 / l^2)
// Round-15 (= r14 resubmit after infra failure): exact-residency design.
//  r8-r13 lesson: every schedule/operand variant pins at 35-37us; r11's clean
//  profile shows Occupancy 30.7% (2048 blocks = 8/CU but LDS caps 5 resident ->
//  batched execution, ~2.5 waves/SIMD average) while VALU busy time == work
//  floor. Fix residency, not schedule:
//   - 512-thread blocks (8 waves), 1024 blocks = 8192 waves = EXACTLY the
//     256CU x 32waves capacity. One batch, zero tail, 8 waves/SIMD throughout.
//   - x staging phase deleted: B-frags built in-register from global x
//     (lane (r,q) reads x[row][q*8..q*8+8) directly; row ssq via the
//     shfl_xor(16,32) q-group reduce). No x LDS traffic, no phase-1 barriers.
//   - s-chunk (256 rows, 32KB) LDS-staged in fragment order, amortized over
//     8 waves. 5 blocks/CU LDS limit >= 4 needed. launch_bounds(512,8).
//  K-pad constant folding kept: acc IS the exp2 argument.
// C/D layout (verified r4 pass): acc[i] -> n-row q*4+i, m-col r.

#define LOG2E_F 1.4426950408889634f

typedef __attribute__((ext_vector_type(8))) short bf16x8;   // 8 bf16 = 4 VGPRs
typedef __attribute__((ext_vector_type(4))) float f32x4;
typedef float v2f_ __attribute__((ext_vector_type(2)));

constexpr int D      = 24;
constexpr int TILES  = 4;    // 16-col tiles per wave -> 64 m per wave
constexpr int WB     = 8;    // waves per block
constexpr int TPB    = 64 * WB;  // 512
constexpr int NSPLIT = 32;   // n-chunks of 256 rows
constexpr int CT     = 16;   // tiles per chunk (256 rows)

__device__ inline unsigned short f32_to_bf16_rne(float f) {
    unsigned u = __builtin_bit_cast(unsigned, f);
    u += 0x7fffu + ((u >> 16) & 1u);
    return (unsigned short)(u >> 16);
}
__device__ inline float bf16_to_f32(unsigned short h) {
    unsigned u = ((unsigned)h) << 16;
    return __builtin_bit_cast(float, u);
}

constexpr unsigned short BF16_ONE = 0x3F80;

__global__ __launch_bounds__(TPB, 8) void ke_fused(
    const float* __restrict__ x, const float* __restrict__ s,
    const float* __restrict__ wts,
    const float* __restrict__ sigma_p, const float* __restrict__ length_p,
    float* __restrict__ out, int M, int N, int MGRP) {
    __shared__ __align__(16) unsigned short sm[16384];  // 32KB: hi [0,8192) lo [8192,16384)
    int t    = threadIdx.x;
    int lane = t & 63;
    int wv   = t >> 6;
    int mg   = blockIdx.x % MGRP;
    int ns   = blockIdx.x / MGRP;
    int r    = lane & 15;
    int q    = lane >> 4;

    float l    = length_p[0];
    float c2   = -0.5f * LOG2E_F / (l * l);
    float m2c2 = -2.f * c2;
    float sg   = sigma_p[0];

    // ---- stage this block's 256 s-rows (n-chunk) into LDS, fragment order.
    // threads 0..255 each prep one row; waves 4..7 idle briefly.
    if (t < 256) {
        int row = ns * 256 + t;
        const float* sr = s + (size_t)row * D;
        float v[24];
        float ssq = 0.f;
#pragma unroll
        for (int i = 0; i < 6; ++i) {
            float4 f = reinterpret_cast<const float4*>(sr)[i];
            v[4*i+0] = f.x; v[4*i+1] = f.y; v[4*i+2] = f.z; v[4*i+3] = f.w;
        }
#pragma unroll
        for (int d = 0; d < 24; ++d) ssq = fmaf(v[d], v[d], ssq);
        float lwt = __log2f(sg * sg * wts[row]) + c2 * ssq;
        lwt = fmaxf(lwt, -20000.f);              // w -> 0: finite, exp2 -> 0
        unsigned short hi[32], lo[32];
#pragma unroll
        for (int d = 0; d < 24; ++d) {
            float vs = m2c2 * v[d];
            unsigned short h = f32_to_bf16_rne(vs);
            hi[d] = h;
            lo[d] = f32_to_bf16_rne(vs - bf16_to_f32(h));
        }
        unsigned short lhi = f32_to_bf16_rne(lwt);
        hi[24] = lhi; hi[25] = f32_to_bf16_rne(lwt - bf16_to_f32(lhi));
        hi[26] = BF16_ONE; hi[27] = BF16_ONE;
        hi[28] = 0; hi[29] = 0; hi[30] = 0; hi[31] = 0;
#pragma unroll
        for (int d = 24; d < 32; ++d) lo[d] = 0;
        int sb = (t >> 4) * 512 + (t & 15) * 8;  // fragment-order slot base
#pragma unroll
        for (int q2 = 0; q2 < 4; ++q2) {
            bf16x8 vh, vl;
#pragma unroll
            for (int j2 = 0; j2 < 8; ++j2) { vh[j2] = (short)hi[q2*8+j2]; vl[j2] = (short)lo[q2*8+j2]; }
            *reinterpret_cast<bf16x8*>(sm + sb + q2 * 128) = vh;
            *reinterpret_cast<bf16x8*>(sm + 8192 + sb + q2 * 128) = vl;
        }
    }

    // ---- build B fragments (x) in-register from global (overlaps staging).
    // Lane (r,q) of tile j holds x[m0+j*16+r][q*8 .. q*8+8); q==3 is the
    // K-pad constant frag {1,1,cx_hi,cx_lo,0,0,0,0}.
    int m0 = mg * (TILES * 16 * WB) + wv * (TILES * 16);
    bf16x8 bh[TILES], bl[TILES];
#pragma unroll
    for (int j = 0; j < TILES; ++j) {
        int row = m0 + j * 16 + r;
        int qc  = (q < 3) ? q : 2;               // clamped in-bounds load
        const float4* xp = reinterpret_cast<const float4*>(x + (size_t)row * D + qc * 8);
        float4 f0 = xp[0], f1 = xp[1];
        float v8[8] = {f0.x, f0.y, f0.z, f0.w, f1.x, f1.y, f1.z, f1.w};
        float live = (q < 3) ? 1.f : 0.f;
        float psq = 0.f;
#pragma unroll
        for (int e = 0; e < 8; ++e) psq = fmaf(v8[e], v8[e], psq);
        psq *= live;
        // q-group reduce -> full row ssq in every lane of the group
        psq += __shfl_xor(psq, 16, 64);
        psq += __shfl_xor(psq, 32, 64);
        float cxv = c2 * psq;
        if (q < 3) {
#pragma unroll
            for (int e = 0; e < 8; ++e) {
                unsigned short h = f32_to_bf16_rne(v8[e]);
                bh[j][e] = (short)h;
                bl[j][e] = (short)f32_to_bf16_rne(v8[e] - bf16_to_f32(h));
            }
        } else {
            unsigned short chv = f32_to_bf16_rne(cxv);
            bh[j][0] = (short)BF16_ONE; bh[j][1] = (short)BF16_ONE;
            bh[j][2] = (short)chv;
            bh[j][3] = (short)f32_to_bf16_rne(cxv - bf16_to_f32(chv));
            bh[j][4] = 0; bh[j][5] = 0; bh[j][6] = 0; bh[j][7] = 0;
#pragma unroll
            for (int e = 0; e < 8; ++e) bl[j][e] = 0;
        }
    }
#pragma unroll
    for (int j = 0; j < TILES; ++j) { asm("" : "+v"(bh[j]), "+v"(bl[j])); }

    __syncthreads();

    // ---- main loop: 16 tiles from LDS (fragment order, conflict-free)
    float p[TILES] = {0.f, 0.f, 0.f, 0.f};
#pragma unroll 1
    for (int tt = 0; tt < CT; ++tt) {
        bf16x8 ah = *reinterpret_cast<const bf16x8*>(sm + ((size_t)tt * 64 + lane) * 8);
        bf16x8 al = *reinterpret_cast<const bf16x8*>(sm + 8192 + ((size_t)tt * 64 + lane) * 8);
#pragma unroll
        for (int j = 0; j < TILES; ++j) {
            f32x4 z = {0.f, 0.f, 0.f, 0.f};
            f32x4 acc = __builtin_amdgcn_mfma_f32_16x16x32_bf16(ah, bh[j], z, 0, 0, 0);
            acc = __builtin_amdgcn_mfma_f32_16x16x32_bf16(al, bh[j], acc, 0, 0, 0);
            acc = __builtin_amdgcn_mfma_f32_16x16x32_bf16(ah, bl[j], acc, 0, 0, 0);
            float e0 = __builtin_amdgcn_exp2f(acc[0]);
            float e1 = __builtin_amdgcn_exp2f(acc[1]);
            float e2 = __builtin_amdgcn_exp2f(acc[2]);
            float e3 = __builtin_amdgcn_exp2f(acc[3]);
            p[j] += (e0 + e1) + (e2 + e3);
        }
    }
    // reduce over the 4 q-quarters (column r fixed) and accumulate
#pragma unroll
    for (int j = 0; j < TILES; ++j) {
        p[j] += __shfl_xor(p[j], 16, 64);
        p[j] += __shfl_xor(p[j], 32, 64);
    }
    if (lane < 16) {
#pragma unroll
        for (int j = 0; j < TILES; ++j)
            atomicAdd(&out[m0 + j * 16 + r], p[j]);
    }
}

// ---- fallback: fp32 VALU kernel (no workspace needed)
constexpr int FTPB = 256;
constexpr int MPT  = 2;
constexpr int MBLK = FTPB * MPT;

__global__ __launch_bounds__(FTPB) void ke_plain(
    const float* __restrict__ x, const float* __restrict__ samples,
    const float* __restrict__ weights, const float* __restrict__ sigma_p,
    const float* __restrict__ length_p, float* __restrict__ out,
    int M, int N, int nsplit, int chunk) {
    int mb = blockIdx.x / nsplit;
    int ns = blockIdx.x - mb * nsplit;
    int t  = threadIdx.x;
    int m0 = mb * MBLK + t;
    int m1 = m0 + FTPB;
    int m0c = (m0 < M) ? m0 : 0;
    int m1c = (m1 < M) ? m1 : 0;

    v2f_ xaq[D / 2], xbq[D / 2];
    const v2f_* xp0 = reinterpret_cast<const v2f_*>(x + (size_t)m0c * D);
    const v2f_* xp1 = reinterpret_cast<const v2f_*>(x + (size_t)m1c * D);
#pragma unroll
    for (int qq = 0; qq < D / 2; ++qq) { xaq[qq] = xp0[qq]; xbq[qq] = xp1[qq]; }
#pragma unroll
    for (int qq = 0; qq < D / 2; ++qq) { asm("" : "+v"(xaq[qq])); asm("" : "+v"(xbq[qq])); }

    float l   = length_p[0];
    float c   = -0.5f * LOG2E_F / (l * l);
    float m2c = -2.f * c;
    float sg  = sigma_p[0];
    float sg2 = sg * sg;

    v2f_ qa = {0.f, 0.f}, qb = {0.f, 0.f};
#pragma unroll
    for (int qq = 0; qq < D / 2; ++qq) {
        qa = __builtin_elementwise_fma(xaq[qq], xaq[qq], qa);
        qb = __builtin_elementwise_fma(xbq[qq], xbq[qq], qb);
    }
    float cxa = c * (qa.x + qa.y);
    float cxb = c * (qb.x + qb.y);

    float acc0 = 0.f, acc1 = 0.f;
    int n0 = ns * chunk;
    int n1 = n0 + chunk;
    if (n1 > N) n1 = N;
#pragma unroll 2
    for (int n = n0; n < n1; ++n) {
        const v2f_* s2 = reinterpret_cast<const v2f_*>(samples + (size_t)n * D);
        v2f_ da = {0.f, 0.f}, db = {0.f, 0.f}, sq = {0.f, 0.f};
#pragma unroll
        for (int qq = 0; qq < D / 2; ++qq) {
            v2f_ sv = s2[qq];
            sq = __builtin_elementwise_fma(sv, sv, sq);
            da = __builtin_elementwise_fma(sv, xaq[qq], da);
            db = __builtin_elementwise_fma(sv, xbq[qq], db);
        }
        float cn = c * (sq.x + sq.y);
        float wn = sg2 * weights[n];
        float e0 = fmaf(m2c, da.x + da.y, cn);
        float e1 = fmaf(m2c, db.x + db.y, cn);
        acc0 = fmaf(wn, __builtin_amdgcn_exp2f(e0), acc0);
        acc1 = fmaf(wn, __builtin_amdgcn_exp2f(e1), acc1);
    }
    if (m0 < M) atomicAdd(&out[m0], acc0 * __builtin_amdgcn_exp2f(cxa));
    if (m1 < M) atomicAdd(&out[m1], acc1 * __builtin_amdgcn_exp2f(cxb));
}

extern "C" void kernel_launch(void* const* d_in, const int* in_sizes, int n_in,
                              void* d_out, int out_size, void* d_ws, size_t ws_size,
                              hipStream_t stream) {
    const float* x       = (const float*)d_in[0];
    const float* samples = (const float*)d_in[1];
    const float* weights = (const float*)d_in[2];
    const float* sigma_p = (const float*)d_in[3];
    const float* length_p= (const float*)d_in[4];
    float* out = (float*)d_out;

    int M = in_sizes[0] / D;
    int N = in_sizes[1] / D;

    hipMemsetAsync(out, 0, (size_t)out_size * sizeof(float), stream);

    int MSPAN = TILES * 16 * WB;                 // 512 m per block
    bool fused_ok = (M % MSPAN) == 0 && (N == NSPLIT * CT * 16) && out_size >= M;

    if (fused_ok) {
        int MGRP   = M / MSPAN;                  // 32
        int blocks = MGRP * NSPLIT;              // 1024 = exact device capacity
        ke_fused<<<dim3(blocks), dim3(TPB), 0, stream>>>(
            x, samples, weights, sigma_p, length_p, out, M, N, MGRP);
    } else {
        int mbcnt  = (M + MBLK - 1) / MBLK;
        int nsplit = 2048 / (mbcnt > 0 ? mbcnt : 1);
        if (nsplit < 1) nsplit = 1;
        if (nsplit > N) nsplit = N;
        int chunk = (N + nsplit - 1) / nsplit;
        ke_plain<<<dim3(mbcnt * nsplit), dim3(FTPB), 0, stream>>>(
            x, samples, weights, sigma_p, length_p, out, M, N, nsplit, chunk);
    }
}